// Round 14
// baseline (2750.402 us; speedup 1.0000x reference)
//
#include <hip/hip_runtime.h>
#include <hip/hip_fp16.h>

#define TT 2048
#define BB 64
#define HH 128
#define GG 512   // 4H
#define CH 64    // chunk (timesteps per pipeline phase)
#define NCH (TT / CH)

typedef _Float16 f16x8 __attribute__((ext_vector_type(8)));
typedef _Float16 f16x4 __attribute__((ext_vector_type(4)));
typedef float f32x4 __attribute__((ext_vector_type(4)));

__device__ __forceinline__ float sigm(float x) {
    return __builtin_amdgcn_rcpf(1.0f + __expf(-x));
}
__device__ __forceinline__ float tanh_f(float x) {
    return 1.0f - 2.0f * __builtin_amdgcn_rcpf(1.0f + __expf(2.0f * x));
}
// LDS-only barrier: no vmcnt drain.
__device__ __forceinline__ void bar_lds() {
    asm volatile("s_waitcnt lgkmcnt(0)\n\ts_barrier" ::: "memory");
}

__device__ __forceinline__ f16x8 load_frag(const float* rowp, int kt, int lh) {
    const float4* p4 = (const float4*)(rowp + kt * 32 + lh * 8);
    float4 a = p4[0], b = p4[1];
    f16x8 f;
    f[0] = (_Float16)a.x; f[1] = (_Float16)a.y; f[2] = (_Float16)a.z; f[3] = (_Float16)a.w;
    f[4] = (_Float16)b.x; f[5] = (_Float16)b.y; f[6] = (_Float16)b.z; f[7] = (_Float16)b.w;
    return f;
}

// Round-14: producer/consumer MERGED into one 16-wave block per batch.
// Grid 64, block 1024. Waves 0-7: L0 recurrence (phase cc runs steps of chunk
// cc). Waves 8-15: L1 recurrence (phase cc runs chunk cc-1, gates from LDS Qs)
// + chunk GEMM at phase boundary (Qs <- b1 + W_ih1 . Hc). All inter-stage
// traffic in LDS (Hc replaces r12's h0g HBM round-trip; no flags/atomics).
// 4 waves/SIMD (vs r12's 2) is the lever: r12/r13 showed ~1000 cyc/step of
// unhidden dependency latency; 4 independent streams/SIMD fill it.
// Each wave carries ONE pinned 64-frag weight set (proven-resident shape;
// launch_bounds(1024) caps at 128 VGPR = 4 waves/SIMD, r12's union was 124).
__global__ __launch_bounds__(1024, 1) void k_fused(
    const float* __restrict__ x, const int* __restrict__ lengths,
    const float* __restrict__ ff_w, const float* __restrict__ ff_b,
    const float* __restrict__ W_ih0, const float* __restrict__ W_hh0,
    const float* __restrict__ b0, const float* __restrict__ W_ih1,
    const float* __restrict__ W_hh1, const float* __restrict__ b1,
    float* __restrict__ pooled) {
    const int b = blockIdx.x;
    const int tid = threadIdx.x;
    const int w = tid >> 6;
    const int lane = tid & 63;
    const int c = lane & 15;
    const int lh = lane >> 4;
    const bool pw = (w < 8);          // producer waves (L0)
    const int wu = pw ? w : (w - 8);
    const int un = 16 * wu + c;
    const bool ard = (c == 0);        // A-frag reader lanes (M=1 row 0)
    const bool wr16 = (lane < 16);    // C row m=0 lanes

    __shared__ float xs[TT];              // 8 KB
    __shared__ _Float16 Hb0[2][HH];       // L0 h double-buffer
    __shared__ _Float16 Hb1[2][HH];       // L1 h double-buffer
    __shared__ _Float16 Hc[CH][136];      // chunk h0 history (+8 pad: GEMM reads)
    __shared__ _Float16 Qs[CH][GG];       // chunk gates, 64 KB

    for (int i = tid; i < TT; i += 1024) xs[i] = x[b * TT + i];
    if (tid < 2 * HH) {
        ((_Float16*)Hb0)[tid] = (_Float16)0.f;
        ((_Float16*)Hb1)[tid] = (_Float16)0.f;
    }

    // one weight set per wave: producers W_hh0 (+rank-1 x-proj consts),
    // consumers W_hh1 (+b1)
    f16x8 Bw[4][4];
    float v[4], u0[4], bb1v[4];
#pragma unroll
    for (int t2 = 0; t2 < 4; ++t2) {
        const int r = t2 * HH + un;
        const float* wsrc = pw ? (W_hh0 + r * HH) : (W_hh1 + r * HH);
#pragma unroll
        for (int kt = 0; kt < 4; ++kt) Bw[t2][kt] = load_frag(wsrc, kt, lh);
        if (pw) {
            const float4* wi4 = (const float4*)(W_ih0 + r * HH);
            const float4* fw4 = (const float4*)ff_w;
            const float4* fb4 = (const float4*)ff_b;
            float vv = 0.f, uu = 0.f;
#pragma unroll
            for (int m = 0; m < HH / 4; ++m) {
                float4 a = wi4[m], fw = fw4[m], fb = fb4[m];
                vv += a.x * fw.x + a.y * fw.y + a.z * fw.z + a.w * fw.w;
                uu += a.x * fb.x + a.y * fb.y + a.z * fb.z + a.w * fb.w;
            }
            v[t2] = vv;
            u0[t2] = uu + b0[r];
            bb1v[t2] = 0.f;
        } else {
            v[t2] = 0.f;
            u0[t2] = 0.f;
            bb1v[t2] = b1[r];
        }
    }
#pragma unroll
    for (int t2 = 0; t2 < 4; ++t2)
#pragma unroll
        for (int kt = 0; kt < 4; ++kt) asm volatile("" : "+v"(Bw[t2][kt]));

    const int len = lengths[b];
    float cst = 0.f, mean = 0.f, mx = -1e30f, lastv = 0.f;
    f16x8 av[4];
#pragma unroll
    for (int kt = 0; kt < 4; ++kt) av[kt] = (f16x8){0, 0, 0, 0, 0, 0, 0, 0};
    __syncthreads();

// One pipeline interval: producer step t=cc*CH+J_ and consumer step
// tc=(cc-1)*CH+J_ run concurrently on their wave halves; RB_ = J_&1.
#define INTERVAL(J_, RB_)                                                       \
    do {                                                                        \
        if (pw) {                                                               \
            if (prun) {                                                         \
                if (ard) {                                                      \
                    _Pragma("unroll") for (int kt = 0; kt < 4; ++kt)            \
                        av[kt] = *(const f16x8*)&Hb0[RB_][kt * 32 + lh * 8];    \
                }                                                               \
                const float xt = xs[tp0 + (J_)];                                \
                float p[4];                                                     \
                _Pragma("unroll") for (int t2 = 0; t2 < 4; ++t2) {              \
                    f32x4 a;                                                    \
                    a[0] = wr16 ? (xt * v[t2] + u0[t2]) : 0.f;                  \
                    a[1] = 0.f; a[2] = 0.f; a[3] = 0.f;                         \
                    _Pragma("unroll") for (int kt = 0; kt < 4; ++kt)            \
                        a = __builtin_amdgcn_mfma_f32_16x16x32_f16(             \
                            av[kt], Bw[t2][kt], a, 0, 0, 0);                    \
                    p[t2] = a[0];                                               \
                }                                                               \
                float gi = sigm(p[0]), gf = sigm(p[1]);                         \
                float gg = tanh_f(p[2]), go = sigm(p[3]);                       \
                cst = gf * cst + gi * gg;                                       \
                float hn = go * tanh_f(cst);                                    \
                if (wr16) {                                                     \
                    Hb0[(RB_) ^ 1][un] = (_Float16)hn;                          \
                    Hc[J_][un] = (_Float16)hn;                                  \
                }                                                               \
            }                                                                   \
        } else if (crun) {                                                      \
            f16x4 qv = *(const f16x4*)&Qs[J_][un * 4];                          \
            if (ard) {                                                          \
                _Pragma("unroll") for (int kt = 0; kt < 4; ++kt)                \
                    av[kt] = *(const f16x8*)&Hb1[RB_][kt * 32 + lh * 8];        \
            }                                                                   \
            float p[4];                                                         \
            _Pragma("unroll") for (int t2 = 0; t2 < 4; ++t2) {                  \
                f32x4 a;                                                        \
                a[0] = wr16 ? (float)qv[t2] : 0.f;                              \
                a[1] = 0.f; a[2] = 0.f; a[3] = 0.f;                             \
                _Pragma("unroll") for (int kt = 0; kt < 4; ++kt)                \
                    a = __builtin_amdgcn_mfma_f32_16x16x32_f16(                 \
                        av[kt], Bw[t2][kt], a, 0, 0, 0);                        \
                p[t2] = a[0];                                                   \
            }                                                                   \
            float gi = sigm(p[0]), gf = sigm(p[1]);                             \
            float gg = tanh_f(p[2]), go = sigm(p[3]);                           \
            cst = gf * cst + gi * gg;                                           \
            float hn = go * tanh_f(cst);                                        \
            if (wr16) Hb1[(RB_) ^ 1][un] = (_Float16)hn;                        \
            const int tc = tc0 + (J_);                                          \
            if (tc < len) { mean += hn; mx = fmaxf(mx, hn); }                   \
            if (tc == len - 1) lastv = hn;                                      \
        }                                                                       \
        bar_lds();                                                              \
    } while (0)

    for (int cc = 0; cc <= NCH; ++cc) {
        const bool prun = (cc < NCH);       // producer active this phase
        const bool crun = (cc >= 1);        // consumer active this phase
        const int tp0 = cc * CH;
        const int tc0 = (cc - 1) * CH;
        for (int j = 0; j < CH; j += 2) {
            INTERVAL(j, 0);
            INTERVAL(j + 1, 1);
        }
        // phase boundary: consumer waves GEMM chunk cc: Qs <- b1 + W_ih1 . Hc
        if (!pw && cc < NCH) {
            f16x8 Bi[4][4];  // transient; reloaded per chunk (33x, off hot path)
#pragma unroll
            for (int t2 = 0; t2 < 4; ++t2)
#pragma unroll
                for (int kt = 0; kt < 4; ++kt)
                    Bi[t2][kt] = load_frag(W_ih1 + (t2 * HH + un) * HH, kt, lh);
#pragma unroll
            for (int mt = 0; mt < 4; ++mt) {
                f16x8 am[4];  // A[m=c][k=kt*32+lh*8+j] from padded Hc
#pragma unroll
                for (int kt = 0; kt < 4; ++kt)
                    am[kt] = *(const f16x8*)&Hc[mt * 16 + c][kt * 32 + lh * 8];
                f32x4 qa[4];
#pragma unroll
                for (int t2 = 0; t2 < 4; ++t2) {
                    qa[t2] = (f32x4){0.f, 0.f, 0.f, 0.f};
#pragma unroll
                    for (int kt = 0; kt < 4; ++kt)
                        qa[t2] = __builtin_amdgcn_mfma_f32_16x16x32_f16(
                            am[kt], Bi[t2][kt], qa[t2], 0, 0, 0);
                }
#pragma unroll
                for (int r = 0; r < 4; ++r) {  // C row m = 4*lh + r
                    f16x4 qv;
#pragma unroll
                    for (int t2 = 0; t2 < 4; ++t2)
                        qv[t2] = (_Float16)(qa[t2][r] + bb1v[t2]);
                    *(f16x4*)&Qs[mt * 16 + 4 * lh + r][un * 4] = qv;
                }
            }
        }
        bar_lds();  // Qs (and Hc reuse) ordered before next phase
    }
#undef INTERVAL

    if (!pw && wr16) {
        pooled[b * 384 + un] = mean / (float)len;
        pooled[b * 384 + 128 + un] = mx;
        pooled[b * 384 + 256 + un] = lastv;
    }
}

// ---------------- head: [B,3H] @ [3H,C]^T + bias ----------------
__global__ __launch_bounds__(448) void k_head(
    const float* __restrict__ pooled, const float* __restrict__ lin_w,
    const float* __restrict__ lin_b, float* __restrict__ out) {
    int tid = threadIdx.x;  // 448 = 64*7
    int b = tid / 7, cc = tid % 7;
    const float* p = pooled + b * 384;
    const float* wr = lin_w + cc * 384;
    float a0 = 0.f, a1 = 0.f, a2 = 0.f, a3 = 0.f;
#pragma unroll
    for (int k = 0; k < 384; k += 4) {
        a0 += p[k + 0] * wr[k + 0];
        a1 += p[k + 1] * wr[k + 1];
        a2 += p[k + 2] * wr[k + 2];
        a3 += p[k + 3] * wr[k + 3];
    }
    out[tid] = lin_b[cc] + ((a0 + a1) + (a2 + a3));
}

extern "C" void kernel_launch(void* const* d_in, const int* in_sizes, int n_in,
                              void* d_out, int out_size, void* d_ws, size_t ws_size,
                              hipStream_t stream) {
    const float* x     = (const float*)d_in[0];
    const int*   lens  = (const int*)d_in[1];
    const float* ff_w  = (const float*)d_in[2];
    const float* ff_b  = (const float*)d_in[3];
    const float* W_ih0 = (const float*)d_in[4];
    const float* W_hh0 = (const float*)d_in[5];
    const float* b0    = (const float*)d_in[6];
    const float* W_ih1 = (const float*)d_in[7];
    const float* W_hh1 = (const float*)d_in[8];
    const float* b1    = (const float*)d_in[9];
    const float* lin_w = (const float*)d_in[10];
    const float* lin_b = (const float*)d_in[11];
    float* out = (float*)d_out;

    float* pooled = (float*)d_ws;  // [64*384] floats

    k_fused<<<dim3(BB), dim3(1024), 0, stream>>>(
        x, lens, ff_w, ff_b, W_ih0, W_hh0, b0, W_ih1, W_hh1, b1, pooled);
    k_head<<<dim3(1), dim3(448), 0, stream>>>(pooled, lin_w, lin_b, out);
}